// Round 17
// baseline (576.810 us; speedup 1.0000x reference)
//
#include <hip/hip_runtime.h>
#include <math.h>

#define NB 4
#define NL 1024
#define ND 1024
#define NH 16
#define HD 64

typedef __attribute__((ext_vector_type(8))) short bf16x8;
typedef __attribute__((ext_vector_type(4))) float f32x4;

static __device__ __forceinline__ unsigned short f32_to_bf16(float f) {
  unsigned u = __float_as_uint(f);
  u += 0x7FFFu + ((u >> 16) & 1u);   // RNE
  return (unsigned short)(u >> 16);
}
static __device__ __forceinline__ float bf16_to_f32(unsigned short s) {
  return __uint_as_float(((unsigned)s) << 16);
}
static __device__ __forceinline__ float exp2_f(float x) {
  float r;
  asm("v_exp_f32 %0, %1" : "=v"(r) : "v"(x));
  return r;
}

// trunc-split 8 fp32 -> hi bf16x8 + lo bf16x8 (residual trunc). err ~2^-16 rel.
static __device__ __forceinline__ void split8(float4 a, float4 b, bf16x8* hi, bf16x8* lo) {
  unsigned u[8] = {__float_as_uint(a.x), __float_as_uint(a.y),
                   __float_as_uint(a.z), __float_as_uint(a.w),
                   __float_as_uint(b.x), __float_as_uint(b.y),
                   __float_as_uint(b.z), __float_as_uint(b.w)};
  union { unsigned p[4]; bf16x8 v; } H, L;
#pragma unroll
  for (int p = 0; p < 4; ++p) {
    unsigned u0 = u[2 * p], u1 = u[2 * p + 1];
    H.p[p] = __builtin_amdgcn_perm(u1, u0, 0x07060302u);
    unsigned l0 = __float_as_uint(__uint_as_float(u0) - __uint_as_float(u0 & 0xFFFF0000u));
    unsigned l1 = __float_as_uint(__uint_as_float(u1) - __uint_as_float(u1 & 0xFFFF0000u));
    L.p[p] = __builtin_amdgcn_perm(l1, l0, 0x07060302u);
  }
  *hi = H.v; *lo = L.v;
}

// ---------------- weight convert (+ zero the amask flag) ----------------
__global__ __launch_bounds__(256) void wcvt_kernel(
    const float* __restrict__ w0, const float* __restrict__ w1,
    const float* __restrict__ w2, const float* __restrict__ w3,
    unsigned short* __restrict__ wb, int* __restrict__ flag)
{
  if (blockIdx.x == 0 && blockIdx.y == 0 && threadIdx.x == 0) flag[0] = 0;
  const int t = blockIdx.y;
  const int o = blockIdx.x;
  const float* w = (t == 0) ? w0 : (t == 1) ? w1 : (t == 2) ? w2 : w3;
  unsigned short* hi = wb + (size_t)t * 6 * (1u << 20);
  unsigned short* lo = hi + 3 * (1u << 20);
  const int tid = threadIdx.x;
  float v[12];
  const float* src = w + (size_t)o * (ND * 3) + tid * 12;
#pragma unroll
  for (int j = 0; j < 3; ++j) {
    float4 f = *(const float4*)(src + j * 4);
    v[j * 4 + 0] = f.x; v[j * 4 + 1] = f.y; v[j * 4 + 2] = f.z; v[j * 4 + 3] = f.w;
  }
#pragma unroll
  for (int k = 0; k < 3; ++k) {
    unsigned short hh[4], ll[4];
#pragma unroll
    for (int ii = 0; ii < 4; ++ii) {
      float x = v[ii * 3 + k];
      unsigned short h = f32_to_bf16(x);
      float r = x - bf16_to_f32(h);
      hh[ii] = h; ll[ii] = f32_to_bf16(r);
    }
    size_t dst = (size_t)k * (ND * ND) + (size_t)o * ND + tid * 4;
    *(ushort4*)&hi[dst] = make_ushort4(hh[0], hh[1], hh[2], hh[3]);
    *(ushort4*)&lo[dst] = make_ushort4(ll[0], ll[1], ll[2], ll[3]);
  }
}

// ---------------- amask zero-scan ----------------
__global__ __launch_bounds__(256) void amask_scan(
    const float* __restrict__ a, int* __restrict__ flag)
{
  size_t i = ((size_t)blockIdx.x * 256 + threadIdx.x) * 4;
  float4 v = *(const float4*)&a[i];
  if (v.x != 0.f || v.y != 0.f || v.z != 0.f || v.w != 0.f) atomicOr(flag, 1);
}

// ---------------- conv-as-GEMM, BM=64 2-phase at 3 blocks/CU ----------------
// Per buffer: A(64x32 f32, 8KB) + Bh(128x32 u16, 8KB) + Bl(8KB) = 24KB;
// double-buffered 48KB -> still 3 blocks/CU. One barrier per K-step: issue
// STAGE(next)->buf^1, compute buf, __syncthreads (its vmcnt drain now has the
// whole compute phase of load-flight behind it). Same math order as R1 ->
// bit-identical output. Edge rows killed at fragment level.
__global__ __launch_bounds__(256, 3) void conv_mfma2(
    const float* X0, const float* X1, const float* X2,
    const unsigned short* __restrict__ wb,
    const float* b0, const float* b1, const float* b2,
    float* Y0, float* Y1, float* Y2, int mode)
{
  __shared__ __align__(16) unsigned char LDSb[2][24576];  // A | Bh | Bl per buf

  const int tid = threadIdx.x, lane = tid & 63, wave = tid >> 6;
  const int lin = blockIdx.x + 8 * (blockIdx.y + 64 * blockIdx.z);
  const int g = lin & 7, t = lin >> 3;
  const int nb = (g & 3) * 2 + (t & 1);
  const int mb = (g >> 2) * 32 + ((t >> 1) & 31);
  const int z  = t >> 6;
  const int n0 = nb * 128, m0 = mb * 64;
  const int b = m0 >> 10, l0v = m0 & (NL - 1);

  const float* X = (mode == 0) ? (z == 0 ? X0 : (z == 1 ? X1 : X2)) : X0;
  const unsigned short* Wh = (mode == 0) ? wb + (size_t)z * 6 * (1u << 20) : wb;
  const unsigned short* Wl = Wh + 3 * (1u << 20);

  const int wm = (wave >> 1) * 32, wn = (wave & 1) * 64;
  const int mrow = lane & 15, quad = lane >> 4;
  const int r16 = lane >> 2, cs = lane & 3;
  const int src_chunk = (cs - (r16 >> 1)) & 3;
  const int bswz = ((quad + (mrow >> 1)) & 3) * 8;

  const int NSTEP = (mode == 0) ? 96 : 32;

  auto stage = [&](int s, int buf) {
    const int koff = (mode == 0) ? (s >> 5) : z;
    const int i0 = ((mode == 0) ? (s & 31) : s) << 5;
    float* AfD = (float*)(LDSb[buf]);
    unsigned short* BhD = (unsigned short*)(LDSb[buf] + 8192);
    unsigned short* BlD = (unsigned short*)(LDSb[buf] + 16384);
#pragma unroll
    for (int s2 = 0; s2 < 2; ++s2) {
      const int seg = wave * 2 + s2;
      const size_t goff = ((size_t)koff << 20) +
                          (size_t)(n0 + seg * 16 + r16) * ND + i0 + src_chunk * 8;
      __builtin_amdgcn_global_load_lds(
          (const __attribute__((address_space(1))) unsigned int*)(Wh + goff),
          (__attribute__((address_space(3))) unsigned int*)&BhD[seg * 512], 16, 0, 0);
      __builtin_amdgcn_global_load_lds(
          (const __attribute__((address_space(1))) unsigned int*)(Wl + goff),
          (__attribute__((address_space(3))) unsigned int*)&BlD[seg * 512], 16, 0, 0);
    }
#pragma unroll
    for (int j = 0; j < 2; ++j) {
      const int s2 = (wave * 2 + j) * 64 + lane;   // [0,512)
      const int row = s2 >> 3, sir = s2 & 7;
      const int chunk = (sir - (row & 7)) & 7;
      int l = l0v + row + koff - 1;
      l = (l < 0) ? 0 : (l > NL - 1 ? NL - 1 : l);
      const float* gp = X + ((size_t)(b << 10) + l) * ND + i0 + chunk * 4;
      __builtin_amdgcn_global_load_lds(
          (const __attribute__((address_space(1))) unsigned int*)gp,
          (__attribute__((address_space(3))) unsigned int*)&AfD[(wave * 2 + j) * 256],
          16, 0, 0);
    }
  };

  f32x4 acc[2][4] = {};
  const bf16x8 zz = {};

  stage(0, 0);
  __syncthreads();
  int cur = 0;
  for (int s = 0; s < NSTEP; ++s) {
    if (s + 1 < NSTEP) stage(s + 1, cur ^ 1);

    const int koff = (mode == 0) ? (s >> 5) : z;
    const bool e_lo = (l0v == 0 && koff == 0);
    const bool e_hi = (l0v == NL - 64 && koff == 2);

    const float* Af = (const float*)(LDSb[cur]);
    const unsigned short* Bh = (const unsigned short*)(LDSb[cur] + 8192);
    const unsigned short* Bl = (const unsigned short*)(LDSb[cur] + 16384);

    bf16x8 ah[2], al[2];
#pragma unroll
    for (int mi = 0; mi < 2; ++mi) {
      const int row = wm + mi * 16 + mrow, r7 = row & 7;
      float4 fa = *(const float4*)&Af[row * 32 + (((quad * 2) + r7) & 7) * 4];
      float4 fb = *(const float4*)&Af[row * 32 + (((quad * 2 + 1) + r7) & 7) * 4];
      split8(fa, fb, &ah[mi], &al[mi]);
      const bool kill = (e_lo && row == 0) || (e_hi && row == 63);
      if (kill) { ah[mi] = zz; al[mi] = zz; }
    }
#pragma unroll
    for (int ni = 0; ni < 4; ++ni) {
      const int brow = wn + ni * 16 + mrow;
      bf16x8 bh = *(const bf16x8*)&Bh[brow * 32 + bswz];
      bf16x8 bl = *(const bf16x8*)&Bl[brow * 32 + bswz];
#pragma unroll
      for (int mi = 0; mi < 2; ++mi) {
        acc[mi][ni] = __builtin_amdgcn_mfma_f32_16x16x32_bf16(ah[mi], bh, acc[mi][ni], 0, 0, 0);
        acc[mi][ni] = __builtin_amdgcn_mfma_f32_16x16x32_bf16(ah[mi], bl, acc[mi][ni], 0, 0, 0);
        acc[mi][ni] = __builtin_amdgcn_mfma_f32_16x16x32_bf16(al[mi], bh, acc[mi][ni], 0, 0, 0);
      }
    }
    __syncthreads();
    cur ^= 1;
  }

  if (mode == 0) {
    const float* bias = (z == 0) ? b0 : (z == 1) ? b1 : b2;
    unsigned short* U = (unsigned short*)Y0;
    const size_t PLs = (size_t)4096 * 1024;
    if (z < 2) {
      // Q (scaled) or K: split hi/lo bf16 planes [bh][l][64]
      unsigned short* Ph = U + (size_t)(2 * z) * PLs;
      unsigned short* Pl = Ph + PLs;
      const float sc = (z == 0) ? 0.18033688011112042f : 1.0f;  // 0.125*log2(e) for Q
#pragma unroll
      for (int ni = 0; ni < 4; ++ni) {
        const int n = n0 + wn + ni * 16 + mrow;
        const float bv = bias[n];
        const int h = n >> 6, dd = n & 63;
        const int bh = b * NH + h;
#pragma unroll
        for (int mi = 0; mi < 2; ++mi) {
          const int mbase = m0 + wm + mi * 16 + quad * 4;
          f32x4 v = acc[mi][ni];
#pragma unroll
          for (int r = 0; r < 4; ++r) {
            const int l = (mbase + r) & (NL - 1);
            const float val = (v[r] + bv) * sc;
            const unsigned u = __float_as_uint(val);
            const unsigned short hh = (unsigned short)(u >> 16);     // trunc hi
            const float res = val - __uint_as_float(u & 0xFFFF0000u);
            const unsigned short ll = (unsigned short)(__float_as_uint(res) >> 16);
            const size_t off = ((size_t)bh * NL + l) * HD + dd;
            Ph[off] = hh; Pl[off] = ll;
          }
        }
      }
    } else {
      // V: bf16 transposed plane [bh][dd][l] -> ushort4 stores (l-contiguous)
      unsigned short* Pv = U + (size_t)4 * PLs;
#pragma unroll
      for (int ni = 0; ni < 4; ++ni) {
        const int n = n0 + wn + ni * 16 + mrow;
        const float bv = bias[n];
        const int h = n >> 6, dd = n & 63;
        const int bh = b * NH + h;
#pragma unroll
        for (int mi = 0; mi < 2; ++mi) {
          const int mbase = m0 + wm + mi * 16 + quad * 4;
          const int lb = mbase & (NL - 1);
          f32x4 v = acc[mi][ni];
          ushort4 s4 = make_ushort4(f32_to_bf16(v[0] + bv), f32_to_bf16(v[1] + bv),
                                    f32_to_bf16(v[2] + bv), f32_to_bf16(v[3] + bv));
          *(ushort4*)&Pv[((size_t)bh * HD + dd) * NL + lb] = s4;
        }
      }
    }
  } else {
    float* P = Y0 + (size_t)z * ((size_t)NB * NL * ND);
#pragma unroll
    for (int ni = 0; ni < 4; ++ni) {
      const int n = n0 + wn + ni * 16 + mrow;
#pragma unroll
      for (int mi = 0; mi < 2; ++mi) {
        const int mbase = m0 + wm + mi * 16 + quad * 4;
        f32x4 v = acc[mi][ni];
#pragma unroll
        for (int r = 0; r < 4; ++r) {
          const int l = (mbase + r) & (NL - 1);
          P[((size_t)(b << 10) + l) * ND + n] = v[r];
        }
      }
    }
  }
}

// ---------------- reduce ----------------
__global__ __launch_bounds__(256) void reduce_kernel(
    const float* __restrict__ P, const float* __restrict__ bias, float* __restrict__ out)
{
  const size_t S = (size_t)NB * NL * ND;
  const size_t idx = ((size_t)blockIdx.x * 256 + threadIdx.x) * 4;
  const int n = (int)(idx & (ND - 1));
  float4 p0 = *(const float4*)&P[idx];
  float4 p1 = *(const float4*)&P[idx + S];
  float4 p2 = *(const float4*)&P[idx + 2 * S];
  float4 bv = *(const float4*)&bias[n];
  float4 r;
  r.x = p0.x + p1.x + p2.x + bv.x;
  r.y = p0.y + p1.y + p2.y + bv.y;
  r.z = p0.z + p1.z + p2.z + bv.z;
  r.w = p0.w + p1.w + p2.w + bv.w;
  *(float4*)&out[idx] = r;
}

// ---------------- MFMA flash attention (R1-proven: QBLK=64) ----------------
// Inputs attn-ready: Qhi/Qlo/Khi/Klo [bh][l][64] (Q prescaled 0.125*log2e),
// Vt bf16 [bh][dd][l]. All tile staging = pure global_load_lds (rotated source,
// linear LDS dest, 64-ushort rows -> 2-way bank aliasing only).
// St = K.Q^T (log2 domain), online softmax with defer-max, O^T = V^T.P^T.
__global__ __launch_bounds__(256, 3) void attn_mfma(
    const unsigned short* __restrict__ U, const int* __restrict__ kpm,
    const float* __restrict__ amask, const int* __restrict__ aflagp,
    float* __restrict__ AO)
{
  __shared__ __align__(16) unsigned short S[3 * 4096];  // Kh | Kl | Vt (64x64 each)
  __shared__ __align__(16) float Fm[NL];                // key mask: 0 or -inf
  unsigned short* Kh = S;
  unsigned short* Kl = S + 4096;
  unsigned short* Vt = S + 8192;

  const int tid = threadIdx.x, lane = tid & 63, wave = tid >> 6;
  const int c = lane & 15, quad = lane >> 4;
  const int lin = blockIdx.x;
  const int bh = (lin & 7) + 8 * (lin >> 7);      // same bh -> same XCD (lin%8)
  const int mt = (lin >> 3) & 15;
  const int b = bh >> 4;
  const int m0 = mt * 64;
  const int aflag = *aflagp;
  const int mrow = wave * 16 + c;                 // this lane's q-row (local)
  const int gm = m0 + mrow;

  const size_t PLs = (size_t)4096 * 1024;
  const unsigned short* qTh = U;
  const unsigned short* qTl = U + PLs;
  const unsigned short* kTh = U + 2 * PLs;
  const unsigned short* kTl = U + 3 * PLs;
  const unsigned short* vTt = U + 4 * PLs;

  // staging lane geometry: each instr = 8 rows x 8 slots of 8 ushorts (16B/lane)
  const int srow = lane >> 3;                     // row within 8-row group
  const int slot = lane & 7;
  const int chunk = (slot - srow) & 7;            // rotated source chunk

  // ---- stage Q into Kh/Kl (16 instrs, 4/wave) ----
#pragma unroll
  for (int q = 0; q < 4; ++q) {
    const int pl = q >> 1;
    const int i = wave * 2 + (q & 1);
    const int row = i * 8 + srow;
    const unsigned short* src = (pl ? qTl : qTh) +
        ((size_t)bh * NL + m0 + row) * HD + chunk * 8;
    unsigned short* dst = (pl ? Kl : Kh) + i * 512;
    __builtin_amdgcn_global_load_lds(
        (const __attribute__((address_space(1))) unsigned int*)src,
        (__attribute__((address_space(3))) unsigned int*)dst, 16, 0, 0);
  }
  // ---- key-padding-mask LUT ----
  {
    int4 kv = *(const int4*)&kpm[b * NL + tid * 4];
    float4 f;
    f.x = kv.x ? -INFINITY : 0.f;
    f.y = kv.y ? -INFINITY : 0.f;
    f.z = kv.z ? -INFINITY : 0.f;
    f.w = kv.w ? -INFINITY : 0.f;
    *(float4*)&Fm[tid * 4] = f;
  }
  __syncthreads();
  // ---- Q B-frags to registers ----
  bf16x8 qbh[2], qbl[2];
#pragma unroll
  for (int kb = 0; kb < 2; ++kb) {
    const int cso = ((kb * 4 + quad + mrow) & 7) * 8;
    qbh[kb] = *(const bf16x8*)&Kh[mrow * 64 + cso];
    qbl[kb] = *(const bf16x8*)&Kl[mrow * 64 + cso];
  }

  f32x4 acc[4] = {};            // O^T frags: dd = df*16 + quad*4 + r, col = q-row
  float m_r = -INFINITY, l_r = 0.0f;

  for (int n0t = 0; n0t < NL; n0t += 64) {
    __syncthreads();            // frags/compute of prev tile done before restaging

    // ---- stage K hi/lo + V^T tile: 24 global_load_lds (6/wave) ----
#pragma unroll
    for (int q = 0; q < 6; ++q) {
      const int pl = q >> 1;    // 0=Kh 1=Kl 2=Vt (compile-time after unroll)
      const int i = wave * 2 + (q & 1);
      const int row = i * 8 + srow;
      const unsigned short* src;
      unsigned short* dst;
      if (pl == 0)      { src = kTh + ((size_t)bh * NL + n0t + row) * HD + chunk * 8; dst = Kh + i * 512; }
      else if (pl == 1) { src = kTl + ((size_t)bh * NL + n0t + row) * HD + chunk * 8; dst = Kl + i * 512; }
      else              { src = vTt + ((size_t)bh * HD + row) * NL + n0t + chunk * 8; dst = Vt + i * 512; }
      __builtin_amdgcn_global_load_lds(
          (const __attribute__((address_space(1))) unsigned int*)src,
          (__attribute__((address_space(3))) unsigned int*)dst, 16, 0, 0);
    }

    // ---- masks for this lane's 16 score slots from LDS LUT ----
    float mval[4][4];
#pragma unroll
    for (int nf = 0; nf < 4; ++nf) {
      float4 fm = *(const float4*)&Fm[n0t + nf * 16 + quad * 4];
      mval[nf][0] = fm.x; mval[nf][1] = fm.y; mval[nf][2] = fm.z; mval[nf][3] = fm.w;
    }
    if (aflag) {
#pragma unroll
      for (int nf = 0; nf < 4; ++nf)
#pragma unroll
        for (int r = 0; r < 4; ++r) {
          const int gn = n0t + nf * 16 + quad * 4 + r;
          mval[nf][r] += amask[(size_t)gm * NL + gn] * 1.4426950408889634f;
        }
    }
    __syncthreads();

    // ---- St = K.Q^T (3-MFMA split), log2 domain ----
    f32x4 sa[4] = {};
    __builtin_amdgcn_s_setprio(1);
#pragma unroll
    for (int kb = 0; kb < 2; ++kb)
#pragma unroll
      for (int nf = 0; nf < 4; ++nf) {
        const int row = nf * 16 + c;
        const int cso = ((kb * 4 + quad + row) & 7) * 8;
        bf16x8 kah = *(const bf16x8*)&Kh[row * 64 + cso];
        bf16x8 kal = *(const bf16x8*)&Kl[row * 64 + cso];
        sa[nf] = __builtin_amdgcn_mfma_f32_16x16x32_bf16(kah, qbh[kb], sa[nf], 0, 0, 0);
        sa[nf] = __builtin_amdgcn_mfma_f32_16x16x32_bf16(kah, qbl[kb], sa[nf], 0, 0, 0);
        sa[nf] = __builtin_amdgcn_mfma_f32_16x16x32_bf16(kal, qbh[kb], sa[nf], 0, 0, 0);
      }
    __builtin_amdgcn_s_setprio(0);

    // ---- online softmax (exp2) with defer-max (THR=8) ----
    float p[4][4];
    float tmax = -INFINITY;
#pragma unroll
    for (int nf = 0; nf < 4; ++nf)
#pragma unroll
      for (int r = 0; r < 4; ++r) {
        float s = sa[nf][r] + mval[nf][r];
        p[nf][r] = s;
        tmax = fmaxf(tmax, s);
      }
    tmax = fmaxf(tmax, __shfl_xor(tmax, 16));
    tmax = fmaxf(tmax, __shfl_xor(tmax, 32));
    float rs = 0.f;
    if (__all(tmax - m_r <= 8.0f)) {
      const float msafe = m_r;
#pragma unroll
      for (int nf = 0; nf < 4; ++nf)
#pragma unroll
        for (int r = 0; r < 4; ++r) {
          float e = exp2_f(p[nf][r] - msafe);
          p[nf][r] = e;
          rs += e;
        }
      rs += __shfl_xor(rs, 16);
      rs += __shfl_xor(rs, 32);
      l_r += rs;
    } else {
      const float newm = fmaxf(m_r, tmax);
      const float msafe = (newm == -INFINITY) ? 0.f : newm;
      const float alpha = exp2_f(m_r - msafe);
#pragma unroll
      for (int nf = 0; nf < 4; ++nf)
#pragma unroll
        for (int r = 0; r < 4; ++r) {
          float e = exp2_f(p[nf][r] - msafe);
          p[nf][r] = e;
          rs += e;
        }
      rs += __shfl_xor(rs, 16);
      rs += __shfl_xor(rs, 32);
      l_r = l_r * alpha + rs;
      m_r = newm;
#pragma unroll
      for (int df = 0; df < 4; ++df) {
        acc[df][0] *= alpha; acc[df][1] *= alpha;
        acc[df][2] *= alpha; acc[df][3] *= alpha;
      }
    }

    // ---- pack P to bf16 dwords: q16[nf][w] = (p[2w+1]<<16)|p[2w] ----
    unsigned q16[4][2];
#pragma unroll
    for (int nf = 0; nf < 4; ++nf)
#pragma unroll
      for (int w = 0; w < 2; ++w)
        q16[nf][w] = (unsigned)f32_to_bf16(p[nf][2 * w]) |
                     ((unsigned)f32_to_bf16(p[nf][2 * w + 1]) << 16);

    // ---- O^T += V^T . P^T ----
#pragma unroll
    for (int kb = 0; kb < 2; ++kb) {
      union { unsigned d[4]; bf16x8 v; } pb;
#pragma unroll
      for (int w = 0; w < 4; ++w) {
        const int addr = ((((quad & 1) * 2 + (w >> 1)) * 16 + c) << 2);
        unsigned v0 = __builtin_amdgcn_ds_bpermute(addr, (int)q16[2 * kb][w & 1]);
        unsigned v1 = __builtin_amdgcn_ds_bpermute(addr, (int)q16[2 * kb + 1][w & 1]);
        pb.d[w] = (quad >> 1) ? v1 : v0;
      }
      __builtin_amdgcn_s_setprio(1);
#pragma unroll
      for (int df = 0; df < 4; ++df) {
        const int row = df * 16 + c;
        const int cso = ((kb * 4 + quad + row) & 7) * 8;
        bf16x8 va = *(const bf16x8*)&Vt[row * 64 + cso];
        acc[df] = __builtin_amdgcn_mfma_f32_16x16x32_bf16(va, pb.v, acc[df], 0, 0, 0);
      }
      __builtin_amdgcn_s_setprio(0);
    }
  }

  // ---- epilogue: transpose O^T -> O via LDS, coalesced store ----
  __syncthreads();
  const float inv = 1.0f / l_r;
  float* Ob = (float*)S + wave * (16 * 68);
#pragma unroll
  for (int df = 0; df < 4; ++df)
#pragma unroll
    for (int r = 0; r < 4; ++r)
      Ob[c * 68 + df * 16 + quad * 4 + r] = acc[df][r] * inv;
  __syncthreads();
  const int mr2 = lane >> 2, cq2 = lane & 3;
  const int h = bh & 15;
#pragma unroll
  for (int ii = 0; ii < 4; ++ii) {
    const int chunk2 = cq2 * 4 + ii;
    float4 v = *(const float4*)&Ob[mr2 * 68 + chunk2 * 4];
    *(float4*)&AO[((size_t)(b << 10) + (m0 + wave * 16 + mr2)) * ND +
                  h * HD + chunk2 * 4] = v;
  }
}

// ---------------- launch ----------------
extern "C" void kernel_launch(void* const* d_in, const int* in_sizes, int n_in,
                              void* d_out, int out_size, void* d_ws, size_t ws_size,
                              hipStream_t stream) {
  (void)in_sizes; (void)n_in; (void)out_size; (void)ws_size;
  const float* query = (const float*)d_in[0];
  const float* key_  = (const float*)d_in[1];
  const float* value = (const float*)d_in[2];
  const int*   kpm   = (const int*)d_in[3];
  const float* amask = (const float*)d_in[4];
  const float* q_w = (const float*)d_in[5];
  const float* q_b = (const float*)d_in[6];
  const float* k_w = (const float*)d_in[7];
  const float* k_b = (const float*)d_in[8];
  const float* v_w = (const float*)d_in[9];
  const float* v_b = (const float*)d_in[10];
  const float* o_w = (const float*)d_in[11];
  const float* o_b = (const float*)d_in[12];
  float* out = (float*)d_out;

  unsigned short* Wb = (unsigned short*)d_ws;
  unsigned short* U  = (unsigned short*)((char*)d_ws + (size_t)50331648);
  float* P  = (float*)((char*)d_ws + (size_t)50331648);
  float* AO = (float*)d_ws;
  int* flag = (int*)d_out;   // dead until reduce overwrites it

  wcvt_kernel<<<dim3(1024, 4), 256, 0, stream>>>(q_w, k_w, v_w, o_w, Wb, flag);
  amask_scan<<<1024, 256, 0, stream>>>(amask, flag);
  conv_mfma2<<<dim3(8, 64, 3), 256, 0, stream>>>(
      query, key_, value, Wb, q_b, k_b, v_b, (float*)U, (float*)U, (float*)U, 0);
  attn_mfma<<<1024, 256, 0, stream>>>(U, kpm, amask, flag, AO);
  conv_mfma2<<<dim3(8, 64, 3), 256, 0, stream>>>(
      AO, AO, AO, Wb + (size_t)3 * 6 * (1u << 20), o_b, o_b, o_b, P, P, P, 1);
  reduce_kernel<<<4096, 256, 0, stream>>>(P, o_b, out);
}

// Round 21
// 499.519 us; speedup vs baseline: 1.1547x; 1.1547x over previous
//
#include <hip/hip_runtime.h>
#include <math.h>

#define NB 4
#define NL 1024
#define ND 1024
#define NH 16
#define HD 64

typedef __attribute__((ext_vector_type(8))) short bf16x8;
typedef __attribute__((ext_vector_type(4))) float f32x4;

static __device__ __forceinline__ unsigned short f32_to_bf16(float f) {
  unsigned u = __float_as_uint(f);
  u += 0x7FFFu + ((u >> 16) & 1u);   // RNE
  return (unsigned short)(u >> 16);
}
static __device__ __forceinline__ float bf16_to_f32(unsigned short s) {
  return __uint_as_float(((unsigned)s) << 16);
}
static __device__ __forceinline__ float exp2_f(float x) {
  float r;
  asm("v_exp_f32 %0, %1" : "=v"(r) : "v"(x));
  return r;
}

// trunc-split 8 fp32 -> hi bf16x8 + lo bf16x8 (residual trunc). err ~2^-16 rel.
static __device__ __forceinline__ void split8(float4 a, float4 b, bf16x8* hi, bf16x8* lo) {
  unsigned u[8] = {__float_as_uint(a.x), __float_as_uint(a.y),
                   __float_as_uint(a.z), __float_as_uint(a.w),
                   __float_as_uint(b.x), __float_as_uint(b.y),
                   __float_as_uint(b.z), __float_as_uint(b.w)};
  union { unsigned p[4]; bf16x8 v; } H, L;
#pragma unroll
  for (int p = 0; p < 4; ++p) {
    unsigned u0 = u[2 * p], u1 = u[2 * p + 1];
    H.p[p] = __builtin_amdgcn_perm(u1, u0, 0x07060302u);
    unsigned l0 = __float_as_uint(__uint_as_float(u0) - __uint_as_float(u0 & 0xFFFF0000u));
    unsigned l1 = __float_as_uint(__uint_as_float(u1) - __uint_as_float(u1 & 0xFFFF0000u));
    L.p[p] = __builtin_amdgcn_perm(l1, l0, 0x07060302u);
  }
  *hi = H.v; *lo = L.v;
}

// ---------------- weight convert (+ zero the amask flag) ----------------
__global__ __launch_bounds__(256) void wcvt_kernel(
    const float* __restrict__ w0, const float* __restrict__ w1,
    const float* __restrict__ w2, const float* __restrict__ w3,
    unsigned short* __restrict__ wb, int* __restrict__ flag)
{
  if (blockIdx.x == 0 && blockIdx.y == 0 && threadIdx.x == 0) flag[0] = 0;
  const int t = blockIdx.y;
  const int o = blockIdx.x;
  const float* w = (t == 0) ? w0 : (t == 1) ? w1 : (t == 2) ? w2 : w3;
  unsigned short* hi = wb + (size_t)t * 6 * (1u << 20);
  unsigned short* lo = hi + 3 * (1u << 20);
  const int tid = threadIdx.x;
  float v[12];
  const float* src = w + (size_t)o * (ND * 3) + tid * 12;
#pragma unroll
  for (int j = 0; j < 3; ++j) {
    float4 f = *(const float4*)(src + j * 4);
    v[j * 4 + 0] = f.x; v[j * 4 + 1] = f.y; v[j * 4 + 2] = f.z; v[j * 4 + 3] = f.w;
  }
#pragma unroll
  for (int k = 0; k < 3; ++k) {
    unsigned short hh[4], ll[4];
#pragma unroll
    for (int ii = 0; ii < 4; ++ii) {
      float x = v[ii * 3 + k];
      unsigned short h = f32_to_bf16(x);
      float r = x - bf16_to_f32(h);
      hh[ii] = h; ll[ii] = f32_to_bf16(r);
    }
    size_t dst = (size_t)k * (ND * ND) + (size_t)o * ND + tid * 4;
    *(ushort4*)&hi[dst] = make_ushort4(hh[0], hh[1], hh[2], hh[3]);
    *(ushort4*)&lo[dst] = make_ushort4(ll[0], ll[1], ll[2], ll[3]);
  }
}

// ---------------- amask zero-scan ----------------
__global__ __launch_bounds__(256) void amask_scan(
    const float* __restrict__ a, int* __restrict__ flag)
{
  size_t i = ((size_t)blockIdx.x * 256 + threadIdx.x) * 4;
  float4 v = *(const float4*)&a[i];
  if (v.x != 0.f || v.y != 0.f || v.z != 0.f || v.w != 0.f) atomicOr(flag, 1);
}

// ---------------- conv-as-GEMM (proven best: 1-phase, 32KB, 3 blocks/CU) -----
// Issue-bound structure: MfmaUtil ~50% + VALUBusy ~43% = ~93% issue saturation.
// Measured neutral/negative: ASPLIT, xsplit, 2-phase@64KB, BM=64 2-phase.
__global__ __launch_bounds__(256, 3) void conv_mfma2(
    const float* X0, const float* X1, const float* X2,
    const unsigned short* __restrict__ wb,
    const float* b0, const float* b1, const float* b2,
    float* Y0, float* Y1, float* Y2, int mode)
{
  __shared__ float Af[128 * 32];
  __shared__ unsigned short Bh[128 * 32];
  __shared__ unsigned short Bl[128 * 32];

  const int tid = threadIdx.x, lane = tid & 63, wave = tid >> 6;
  const int lin = blockIdx.x + 8 * (blockIdx.y + 32 * blockIdx.z);
  const int g = lin & 7, t = lin >> 3;
  const int nb = (g & 3) * 2 + (t & 1);
  const int mb = (g >> 2) * 16 + ((t >> 1) & 15);
  const int z  = t >> 5;
  const int n0 = nb * 128, m0 = mb * 128;
  const int b = m0 >> 10, l0v = m0 & (NL - 1);

  const float* X = (mode == 0) ? (z == 0 ? X0 : (z == 1 ? X1 : X2)) : X0;
  const unsigned short* Wh = (mode == 0) ? wb + (size_t)z * 6 * (1u << 20) : wb;
  const unsigned short* Wl = Wh + 3 * (1u << 20);

  const int wm = (wave >> 1) * 64, wn = (wave & 1) * 64;
  const int mrow = lane & 15, quad = lane >> 4;
  const int r16 = lane >> 2, cs = lane & 3;
  const int src_chunk = (cs - (r16 >> 1)) & 3;
  const int bswz = ((quad + (mrow >> 1)) & 3) * 8;

  f32x4 acc[4][4] = {};

  const int kbeg = (mode == 0) ? 0 : z;
  const int kend = (mode == 0) ? 3 : z + 1;
  for (int koff = kbeg; koff < kend; ++koff) {
    const bool edge_lo = (l0v == 0 && koff == 0);
    const bool edge_hi = (l0v == NL - 128 && koff == 2);
    for (int i0 = 0; i0 < ND; i0 += 32) {
#pragma unroll
      for (int s = 0; s < 2; ++s) {
        const int seg = wave * 2 + s;
        const size_t goff = ((size_t)koff << 20) +
                            (size_t)(n0 + seg * 16 + r16) * ND + i0 + src_chunk * 8;
        __builtin_amdgcn_global_load_lds(
            (const __attribute__((address_space(1))) unsigned int*)(Wh + goff),
            (__attribute__((address_space(3))) unsigned int*)&Bh[seg * 512], 16, 0, 0);
        __builtin_amdgcn_global_load_lds(
            (const __attribute__((address_space(1))) unsigned int*)(Wl + goff),
            (__attribute__((address_space(3))) unsigned int*)&Bl[seg * 512], 16, 0, 0);
      }
#pragma unroll
      for (int j = 0; j < 4; ++j) {
        const int s = (wave * 4 + j) * 64 + lane;
        const int row = s >> 3, sir = s & 7;
        const int chunk = (sir - (row & 7)) & 7;
        int l = l0v + row + koff - 1;
        l = (l < 0) ? 0 : (l > NL - 1 ? NL - 1 : l);
        const float* gp = X + ((size_t)(b << 10) + l) * ND + i0 + chunk * 4;
        __builtin_amdgcn_global_load_lds(
            (const __attribute__((address_space(1))) unsigned int*)gp,
            (__attribute__((address_space(3))) unsigned int*)&Af[(wave * 4 + j) * 256],
            16, 0, 0);
      }
      __syncthreads();
      if (edge_lo || edge_hi) {
        const int er = edge_lo ? 0 : 127;
        if (tid < 8) *(float4*)&Af[er * 32 + tid * 4] = make_float4(0.f, 0.f, 0.f, 0.f);
        __syncthreads();
      }
      bf16x8 ah[4], al[4];
#pragma unroll
      for (int mi = 0; mi < 4; ++mi) {
        const int row = wm + mi * 16 + mrow, r7 = row & 7;
        float4 fa = *(const float4*)&Af[row * 32 + (((quad * 2) + r7) & 7) * 4];
        float4 fb = *(const float4*)&Af[row * 32 + (((quad * 2 + 1) + r7) & 7) * 4];
        split8(fa, fb, &ah[mi], &al[mi]);
      }
#pragma unroll
      for (int ni = 0; ni < 4; ++ni) {
        const int brow = wn + ni * 16 + mrow;
        bf16x8 bh = *(const bf16x8*)&Bh[brow * 32 + bswz];
        bf16x8 bl = *(const bf16x8*)&Bl[brow * 32 + bswz];
#pragma unroll
        for (int mi = 0; mi < 4; ++mi) {
          acc[mi][ni] = __builtin_amdgcn_mfma_f32_16x16x32_bf16(ah[mi], bh, acc[mi][ni], 0, 0, 0);
          acc[mi][ni] = __builtin_amdgcn_mfma_f32_16x16x32_bf16(ah[mi], bl, acc[mi][ni], 0, 0, 0);
          acc[mi][ni] = __builtin_amdgcn_mfma_f32_16x16x32_bf16(al[mi], bh, acc[mi][ni], 0, 0, 0);
        }
      }
      __syncthreads();
    }
  }

  if (mode == 0) {
    const float* bias = (z == 0) ? b0 : (z == 1) ? b1 : b2;
    unsigned short* U = (unsigned short*)Y0;
    const size_t PLs = (size_t)4096 * 1024;
    if (z < 2) {
      // Q (scaled) or K: split hi/lo bf16 planes [bh][l][64]
      unsigned short* Ph = U + (size_t)(2 * z) * PLs;
      unsigned short* Pl = Ph + PLs;
      const float sc = (z == 0) ? 0.18033688011112042f : 1.0f;  // 0.125*log2(e) for Q
#pragma unroll
      for (int ni = 0; ni < 4; ++ni) {
        const int n = n0 + wn + ni * 16 + mrow;
        const float bv = bias[n];
        const int h = n >> 6, dd = n & 63;
        const int bh = b * NH + h;
#pragma unroll
        for (int mi = 0; mi < 4; ++mi) {
          const int mbase = m0 + wm + mi * 16 + quad * 4;
          f32x4 v = acc[mi][ni];
#pragma unroll
          for (int r = 0; r < 4; ++r) {
            const int l = (mbase + r) & (NL - 1);
            const float val = (v[r] + bv) * sc;
            const unsigned u = __float_as_uint(val);
            const unsigned short hh = (unsigned short)(u >> 16);     // trunc hi
            const float res = val - __uint_as_float(u & 0xFFFF0000u);
            const unsigned short ll = (unsigned short)(__float_as_uint(res) >> 16);
            const size_t off = ((size_t)bh * NL + l) * HD + dd;
            Ph[off] = hh; Pl[off] = ll;
          }
        }
      }
    } else {
      // V: bf16 transposed plane [bh][dd][l] -> ushort4 stores (l-contiguous)
      unsigned short* Pv = U + (size_t)4 * PLs;
#pragma unroll
      for (int ni = 0; ni < 4; ++ni) {
        const int n = n0 + wn + ni * 16 + mrow;
        const float bv = bias[n];
        const int h = n >> 6, dd = n & 63;
        const int bh = b * NH + h;
#pragma unroll
        for (int mi = 0; mi < 4; ++mi) {
          const int mbase = m0 + wm + mi * 16 + quad * 4;
          const int lb = mbase & (NL - 1);
          f32x4 v = acc[mi][ni];
          ushort4 s4 = make_ushort4(f32_to_bf16(v[0] + bv), f32_to_bf16(v[1] + bv),
                                    f32_to_bf16(v[2] + bv), f32_to_bf16(v[3] + bv));
          *(ushort4*)&Pv[((size_t)bh * HD + dd) * NL + lb] = s4;
        }
      }
    }
  } else {
    float* P = Y0 + (size_t)z * ((size_t)NB * NL * ND);
#pragma unroll
    for (int ni = 0; ni < 4; ++ni) {
      const int n = n0 + wn + ni * 16 + mrow;
#pragma unroll
      for (int mi = 0; mi < 4; ++mi) {
        const int mbase = m0 + wm + mi * 16 + quad * 4;
        f32x4 v = acc[mi][ni];
#pragma unroll
        for (int r = 0; r < 4; ++r) {
          const int l = (mbase + r) & (NL - 1);
          P[((size_t)(b << 10) + l) * ND + n] = v[r];
        }
      }
    }
  }
}

// ---------------- reduce ----------------
__global__ __launch_bounds__(256) void reduce_kernel(
    const float* __restrict__ P, const float* __restrict__ bias, float* __restrict__ out)
{
  const size_t S = (size_t)NB * NL * ND;
  const size_t idx = ((size_t)blockIdx.x * 256 + threadIdx.x) * 4;
  const int n = (int)(idx & (ND - 1));
  float4 p0 = *(const float4*)&P[idx];
  float4 p1 = *(const float4*)&P[idx + S];
  float4 p2 = *(const float4*)&P[idx + 2 * S];
  float4 bv = *(const float4*)&bias[n];
  float4 r;
  r.x = p0.x + p1.x + p2.x + bv.x;
  r.y = p0.y + p1.y + p2.y + bv.y;
  r.z = p0.z + p1.z + p2.z + bv.z;
  r.w = p0.w + p1.w + p2.w + bv.w;
  *(float4*)&out[idx] = r;
}

// ---------------- MFMA flash attention (proven best: QBLK=64) ----------------
// Inputs attn-ready: Qhi/Qlo/Khi/Klo [bh][l][64] (Q prescaled 0.125*log2e),
// Vt bf16 [bh][dd][l]. All tile staging = pure global_load_lds (rotated source,
// linear LDS dest, 64-ushort rows -> 2-way bank aliasing only).
// St = K.Q^T (log2 domain), online softmax with defer-max, O^T = V^T.P^T.
__global__ __launch_bounds__(256, 3) void attn_mfma(
    const unsigned short* __restrict__ U, const int* __restrict__ kpm,
    const float* __restrict__ amask, const int* __restrict__ aflagp,
    float* __restrict__ AO)
{
  __shared__ __align__(16) unsigned short S[3 * 4096];  // Kh | Kl | Vt (64x64 each)
  __shared__ __align__(16) float Fm[NL];                // key mask: 0 or -inf
  unsigned short* Kh = S;
  unsigned short* Kl = S + 4096;
  unsigned short* Vt = S + 8192;

  const int tid = threadIdx.x, lane = tid & 63, wave = tid >> 6;
  const int c = lane & 15, quad = lane >> 4;
  const int lin = blockIdx.x;
  const int bh = (lin & 7) + 8 * (lin >> 7);      // same bh -> same XCD (lin%8)
  const int mt = (lin >> 3) & 15;
  const int b = bh >> 4;
  const int m0 = mt * 64;
  const int aflag = *aflagp;
  const int mrow = wave * 16 + c;                 // this lane's q-row (local)
  const int gm = m0 + mrow;

  const size_t PLs = (size_t)4096 * 1024;
  const unsigned short* qTh = U;
  const unsigned short* qTl = U + PLs;
  const unsigned short* kTh = U + 2 * PLs;
  const unsigned short* kTl = U + 3 * PLs;
  const unsigned short* vTt = U + 4 * PLs;

  // staging lane geometry: each instr = 8 rows x 8 slots of 8 ushorts (16B/lane)
  const int srow = lane >> 3;                     // row within 8-row group
  const int slot = lane & 7;
  const int chunk = (slot - srow) & 7;            // rotated source chunk

  // ---- stage Q into Kh/Kl (16 instrs, 4/wave) ----
#pragma unroll
  for (int q = 0; q < 4; ++q) {
    const int pl = q >> 1;
    const int i = wave * 2 + (q & 1);
    const int row = i * 8 + srow;
    const unsigned short* src = (pl ? qTl : qTh) +
        ((size_t)bh * NL + m0 + row) * HD + chunk * 8;
    unsigned short* dst = (pl ? Kl : Kh) + i * 512;
    __builtin_amdgcn_global_load_lds(
        (const __attribute__((address_space(1))) unsigned int*)src,
        (__attribute__((address_space(3))) unsigned int*)dst, 16, 0, 0);
  }
  // ---- key-padding-mask LUT ----
  {
    int4 kv = *(const int4*)&kpm[b * NL + tid * 4];
    float4 f;
    f.x = kv.x ? -INFINITY : 0.f;
    f.y = kv.y ? -INFINITY : 0.f;
    f.z = kv.z ? -INFINITY : 0.f;
    f.w = kv.w ? -INFINITY : 0.f;
    *(float4*)&Fm[tid * 4] = f;
  }
  __syncthreads();
  // ---- Q B-frags to registers ----
  bf16x8 qbh[2], qbl[2];
#pragma unroll
  for (int kb = 0; kb < 2; ++kb) {
    const int cso = ((kb * 4 + quad + mrow) & 7) * 8;
    qbh[kb] = *(const bf16x8*)&Kh[mrow * 64 + cso];
    qbl[kb] = *(const bf16x8*)&Kl[mrow * 64 + cso];
  }

  f32x4 acc[4] = {};            // O^T frags: dd = df*16 + quad*4 + r, col = q-row
  float m_r = -INFINITY, l_r = 0.0f;

  for (int n0t = 0; n0t < NL; n0t += 64) {
    __syncthreads();            // frags/compute of prev tile done before restaging

    // ---- stage K hi/lo + V^T tile: 24 global_load_lds (6/wave) ----
#pragma unroll
    for (int q = 0; q < 6; ++q) {
      const int pl = q >> 1;    // 0=Kh 1=Kl 2=Vt (compile-time after unroll)
      const int i = wave * 2 + (q & 1);
      const int row = i * 8 + srow;
      const unsigned short* src;
      unsigned short* dst;
      if (pl == 0)      { src = kTh + ((size_t)bh * NL + n0t + row) * HD + chunk * 8; dst = Kh + i * 512; }
      else if (pl == 1) { src = kTl + ((size_t)bh * NL + n0t + row) * HD + chunk * 8; dst = Kl + i * 512; }
      else              { src = vTt + ((size_t)bh * HD + row) * NL + n0t + chunk * 8; dst = Vt + i * 512; }
      __builtin_amdgcn_global_load_lds(
          (const __attribute__((address_space(1))) unsigned int*)src,
          (__attribute__((address_space(3))) unsigned int*)dst, 16, 0, 0);
    }

    // ---- masks for this lane's 16 score slots from LDS LUT ----
    float mval[4][4];
#pragma unroll
    for (int nf = 0; nf < 4; ++nf) {
      float4 fm = *(const float4*)&Fm[n0t + nf * 16 + quad * 4];
      mval[nf][0] = fm.x; mval[nf][1] = fm.y; mval[nf][2] = fm.z; mval[nf][3] = fm.w;
    }
    if (aflag) {
#pragma unroll
      for (int nf = 0; nf < 4; ++nf)
#pragma unroll
        for (int r = 0; r < 4; ++r) {
          const int gn = n0t + nf * 16 + quad * 4 + r;
          mval[nf][r] += amask[(size_t)gm * NL + gn] * 1.4426950408889634f;
        }
    }
    __syncthreads();

    // ---- St = K.Q^T (3-MFMA split), log2 domain ----
    f32x4 sa[4] = {};
    __builtin_amdgcn_s_setprio(1);
#pragma unroll
    for (int kb = 0; kb < 2; ++kb)
#pragma unroll
      for (int nf = 0; nf < 4; ++nf) {
        const int row = nf * 16 + c;
        const int cso = ((kb * 4 + quad + row) & 7) * 8;
        bf16x8 kah = *(const bf16x8*)&Kh[row * 64 + cso];
        bf16x8 kal = *(const bf16x8*)&Kl[row * 64 + cso];
        sa[nf] = __builtin_amdgcn_mfma_f32_16x16x32_bf16(kah, qbh[kb], sa[nf], 0, 0, 0);
        sa[nf] = __builtin_amdgcn_mfma_f32_16x16x32_bf16(kah, qbl[kb], sa[nf], 0, 0, 0);
        sa[nf] = __builtin_amdgcn_mfma_f32_16x16x32_bf16(kal, qbh[kb], sa[nf], 0, 0, 0);
      }
    __builtin_amdgcn_s_setprio(0);

    // ---- online softmax (exp2) with defer-max (THR=8) ----
    float p[4][4];
    float tmax = -INFINITY;
#pragma unroll
    for (int nf = 0; nf < 4; ++nf)
#pragma unroll
      for (int r = 0; r < 4; ++r) {
        float s = sa[nf][r] + mval[nf][r];
        p[nf][r] = s;
        tmax = fmaxf(tmax, s);
      }
    tmax = fmaxf(tmax, __shfl_xor(tmax, 16));
    tmax = fmaxf(tmax, __shfl_xor(tmax, 32));
    float rs = 0.f;
    if (__all(tmax - m_r <= 8.0f)) {
      const float msafe = m_r;
#pragma unroll
      for (int nf = 0; nf < 4; ++nf)
#pragma unroll
        for (int r = 0; r < 4; ++r) {
          float e = exp2_f(p[nf][r] - msafe);
          p[nf][r] = e;
          rs += e;
        }
      rs += __shfl_xor(rs, 16);
      rs += __shfl_xor(rs, 32);
      l_r += rs;
    } else {
      const float newm = fmaxf(m_r, tmax);
      const float msafe = (newm == -INFINITY) ? 0.f : newm;
      const float alpha = exp2_f(m_r - msafe);
#pragma unroll
      for (int nf = 0; nf < 4; ++nf)
#pragma unroll
        for (int r = 0; r < 4; ++r) {
          float e = exp2_f(p[nf][r] - msafe);
          p[nf][r] = e;
          rs += e;
        }
      rs += __shfl_xor(rs, 16);
      rs += __shfl_xor(rs, 32);
      l_r = l_r * alpha + rs;
      m_r = newm;
#pragma unroll
      for (int df = 0; df < 4; ++df) {
        acc[df][0] *= alpha; acc[df][1] *= alpha;
        acc[df][2] *= alpha; acc[df][3] *= alpha;
      }
    }

    // ---- pack P to bf16 dwords: q16[nf][w] = (p[2w+1]<<16)|p[2w] ----
    unsigned q16[4][2];
#pragma unroll
    for (int nf = 0; nf < 4; ++nf)
#pragma unroll
      for (int w = 0; w < 2; ++w)
        q16[nf][w] = (unsigned)f32_to_bf16(p[nf][2 * w]) |
                     ((unsigned)f32_to_bf16(p[nf][2 * w + 1]) << 16);

    // ---- O^T += V^T . P^T ----
#pragma unroll
    for (int kb = 0; kb < 2; ++kb) {
      union { unsigned d[4]; bf16x8 v; } pb;
#pragma unroll
      for (int w = 0; w < 4; ++w) {
        const int addr = ((((quad & 1) * 2 + (w >> 1)) * 16 + c) << 2);
        unsigned v0 = __builtin_amdgcn_ds_bpermute(addr, (int)q16[2 * kb][w & 1]);
        unsigned v1 = __builtin_amdgcn_ds_bpermute(addr, (int)q16[2 * kb + 1][w & 1]);
        pb.d[w] = (quad >> 1) ? v1 : v0;
      }
      __builtin_amdgcn_s_setprio(1);
#pragma unroll
      for (int df = 0; df < 4; ++df) {
        const int row = df * 16 + c;
        const int cso = ((kb * 4 + quad + row) & 7) * 8;
        bf16x8 va = *(const bf16x8*)&Vt[row * 64 + cso];
        acc[df] = __builtin_amdgcn_mfma_f32_16x16x32_bf16(va, pb.v, acc[df], 0, 0, 0);
      }
      __builtin_amdgcn_s_setprio(0);
    }
  }

  // ---- epilogue: transpose O^T -> O via LDS, coalesced store ----
  __syncthreads();
  const float inv = 1.0f / l_r;
  float* Ob = (float*)S + wave * (16 * 68);
#pragma unroll
  for (int df = 0; df < 4; ++df)
#pragma unroll
    for (int r = 0; r < 4; ++r)
      Ob[c * 68 + df * 16 + quad * 4 + r] = acc[df][r] * inv;
  __syncthreads();
  const int mr2 = lane >> 2, cq2 = lane & 3;
  const int h = bh & 15;
#pragma unroll
  for (int ii = 0; ii < 4; ++ii) {
    const int chunk2 = cq2 * 4 + ii;
    float4 v = *(const float4*)&Ob[mr2 * 68 + chunk2 * 4];
    *(float4*)&AO[((size_t)(b << 10) + (m0 + wave * 16 + mr2)) * ND +
                  h * HD + chunk2 * 4] = v;
  }
}

// ---------------- launch ----------------
extern "C" void kernel_launch(void* const* d_in, const int* in_sizes, int n_in,
                              void* d_out, int out_size, void* d_ws, size_t ws_size,
                              hipStream_t stream) {
  (void)in_sizes; (void)n_in; (void)out_size; (void)ws_size;
  const float* query = (const float*)d_in[0];
  const float* key_  = (const float*)d_in[1];
  const float* value = (const float*)d_in[2];
  const int*   kpm   = (const int*)d_in[3];
  const float* amask = (const float*)d_in[4];
  const float* q_w = (const float*)d_in[5];
  const float* q_b = (const float*)d_in[6];
  const float* k_w = (const float*)d_in[7];
  const float* k_b = (const float*)d_in[8];
  const float* v_w = (const float*)d_in[9];
  const float* v_b = (const float*)d_in[10];
  const float* o_w = (const float*)d_in[11];
  const float* o_b = (const float*)d_in[12];
  float* out = (float*)d_out;

  // workspace map: [0,48M) Wb (AO reuses [0,16.7M) after conv0 consumes q/k);
  // [48,88M) U attn planes / [48,96M) P partials; flag at 96M (dead space,
  // ws_size >= 136M proven by R2's presplit run). d_out written only by reduce.
  unsigned short* Wb = (unsigned short*)d_ws;
  unsigned short* U  = (unsigned short*)((char*)d_ws + (size_t)50331648);
  float* P  = (float*)((char*)d_ws + (size_t)50331648);
  float* AO = (float*)d_ws;
  int* flag = (int*)((char*)d_ws + (size_t)100663296);

  wcvt_kernel<<<dim3(1024, 4), 256, 0, stream>>>(q_w, k_w, v_w, o_w, Wb, flag);
  amask_scan<<<1024, 256, 0, stream>>>(amask, flag);
  conv_mfma2<<<dim3(8, 32, 3), 256, 0, stream>>>(
      query, key_, value, Wb, q_b, k_b, v_b, (float*)U, (float*)U, (float*)U, 0);
  attn_mfma<<<1024, 256, 0, stream>>>(U, kpm, amask, flag, AO);
  conv_mfma2<<<dim3(8, 32, 3), 256, 0, stream>>>(
      AO, AO, AO, Wb + (size_t)3 * 6 * (1u << 20), o_b, o_b, o_b, P, P, P, 1);
  reduce_kernel<<<4096, 256, 0, stream>>>(P, o_b, out);
}